// Round 1
// baseline (5671.635 us; speedup 1.0000x reference)
//
#include <hip/hip_runtime.h>

#define NNODE 100000
#define NEDGE 3200000

__device__ __forceinline__ float leaky(float x) { return x > 0.f ? x : 0.2f * x; }

// ---------------------------------------------------------------------------
// FC: per node, compute h = in @ W for two layers (A in wave0, B in wave1),
// plus el = h.al, er = h.ar row reductions. Block = 128 threads = 2 waves.
// ---------------------------------------------------------------------------
template <int DIN, int DOUT>
__global__ __launch_bounds__(128) void fc_kernel(
    const float* __restrict__ inA, const float* __restrict__ inB,
    const float* __restrict__ WA, const float* __restrict__ alA, const float* __restrict__ arA,
    const float* __restrict__ WB, const float* __restrict__ alB, const float* __restrict__ arB,
    float* __restrict__ hA, float* __restrict__ hB,
    float* __restrict__ elA, float* __restrict__ erA,
    float* __restrict__ elB, float* __restrict__ erB)
{
    __shared__ float rowA[DIN], rowB[DIN];
    const int n   = blockIdx.x;
    const int tid = threadIdx.x;
    for (int k = tid; k < DIN; k += 128) {
        rowA[k] = inA[(size_t)n * DIN + k];
        rowB[k] = inB[(size_t)n * DIN + k];
    }
    __syncthreads();

    const int wave = tid >> 6;
    const int lane = tid & 63;
    const float* row = wave ? rowB : rowA;
    const float* W   = wave ? WB : WA;
    const float* al  = wave ? alB : alA;
    const float* ar  = wave ? arB : arA;
    float* h  = wave ? hB : hA;
    float* el = wave ? elB : elA;
    float* er = wave ? erB : erA;

    const int j0 = lane, j1 = lane + 64;
    float acc0 = 0.f, acc1 = 0.f;
#pragma unroll 4
    for (int k = 0; k < DIN; ++k) {
        const float r = row[k];
        const float* Wk = W + k * DOUT;
        if (j0 < DOUT) acc0 += r * Wk[j0];
        if (DOUT > 64) { if (j1 < DOUT) acc1 += r * Wk[j1]; }
    }
    if (j0 < DOUT) h[(size_t)n * DOUT + j0] = acc0;
    if (DOUT > 64) { if (j1 < DOUT) h[(size_t)n * DOUT + j1] = acc1; }

    float cl = 0.f, cr = 0.f;
    if (j0 < DOUT) { cl += acc0 * al[j0]; cr += acc0 * ar[j0]; }
    if (DOUT > 64) { if (j1 < DOUT) { cl += acc1 * al[j1]; cr += acc1 * ar[j1]; } }
#pragma unroll
    for (int off = 32; off > 0; off >>= 1) {
        cl += __shfl_down(cl, off);
        cr += __shfl_down(cr, off);
    }
    if (lane == 0) { el[n] = cl; er[n] = cr; }
}

// ---------------------------------------------------------------------------
// Init: out rows <- bias broadcast, denominators <- 0.  Block = 128, grid = N.
// ---------------------------------------------------------------------------
__global__ __launch_bounds__(128) void init_kernel(
    float* __restrict__ outA, const float* __restrict__ bA,
    float* __restrict__ outB, const float* __restrict__ bB, int dout,
    float* __restrict__ dA, float* __restrict__ dB)
{
    const int n = blockIdx.x, tid = threadIdx.x;
    for (int j = tid; j < dout; j += 128) {
        outA[(size_t)n * dout + j] = bA[j];
        outB[(size_t)n * dout + j] = bB[j];
    }
    if (tid == 0) { dA[n] = 0.f; dB[n] = 0.f; }
}

// ---------------------------------------------------------------------------
// Edge pass 1: denom[dst] += exp(leaky(el[src]+er[dst])) for both layers.
// (segment_max skipped: softmax is shift-invariant; scores are O(1) so no
//  overflow risk in f32.)
// ---------------------------------------------------------------------------
__global__ __launch_bounds__(256) void edge_sum(
    const int* __restrict__ src, const int* __restrict__ dst,
    const float* __restrict__ elA, const float* __restrict__ erA,
    const float* __restrict__ elB, const float* __restrict__ erB,
    float* __restrict__ dA, float* __restrict__ dB)
{
    const int e = blockIdx.x * 256 + threadIdx.x;
    if (e >= NEDGE) return;
    const int s = src[e], d = dst[e];
    const float eA = leaky(elA[s] + erA[d]);
    const float eB = leaky(elB[s] + erB[d]);
    unsafeAtomicAdd(dA + d, expf(eA));
    unsafeAtomicAdd(dB + d, expf(eB));
}

// ---------------------------------------------------------------------------
// Edge pass 2: out[dst] += h[src] * exp(e)/(denom[dst]+1e-9), one wave/edge,
// both layers of the pair.
// ---------------------------------------------------------------------------
template <int DOUT>
__global__ __launch_bounds__(256) void edge_scatter(
    const int* __restrict__ src, const int* __restrict__ dst,
    const float* __restrict__ elA, const float* __restrict__ erA,
    const float* __restrict__ elB, const float* __restrict__ erB,
    const float* __restrict__ dA, const float* __restrict__ dB,
    const float* __restrict__ hA, const float* __restrict__ hB,
    float* __restrict__ outA, float* __restrict__ outB)
{
    const int gt   = blockIdx.x * 256 + threadIdx.x;
    const int e    = gt >> 6;
    const int lane = threadIdx.x & 63;
    if (e >= NEDGE) return;
    const int s = src[e], d = dst[e];
    const float wA = expf(leaky(elA[s] + erA[d])) / (dA[d] + 1e-9f);
    const float wB = expf(leaky(elB[s] + erB[d])) / (dB[d] + 1e-9f);
    const float* hAs = hA + (size_t)s * DOUT;
    const float* hBs = hB + (size_t)s * DOUT;
    float* oA = outA + (size_t)d * DOUT;
    float* oB = outB + (size_t)d * DOUT;
    if (lane < DOUT) {
        unsafeAtomicAdd(oA + lane, hAs[lane] * wA);
        unsafeAtomicAdd(oB + lane, hBs[lane] * wB);
    }
    if (DOUT > 64) {
        if (lane + 64 < DOUT) {
            unsafeAtomicAdd(oA + lane + 64, hAs[lane + 64] * wA);
            unsafeAtomicAdd(oB + lane + 64, hBs[lane + 64] * wB);
        }
    }
}

// ---------------------------------------------------------------------------
extern "C" void kernel_launch(void* const* d_in, const int* in_sizes, int n_in,
                              void* d_out, int out_size, void* d_ws, size_t ws_size,
                              hipStream_t stream)
{
    const float* x   = (const float*)d_in[0];
    const int* ei0   = (const int*)d_in[1];   // [2,E] int32
    const int* ei1   = (const int*)d_in[2];
    const float* W1  = (const float*)d_in[3];
    const float* al1 = (const float*)d_in[4];
    const float* ar1 = (const float*)d_in[5];
    const float* b1  = (const float*)d_in[6];
    const float* W2  = (const float*)d_in[7];
    const float* al2 = (const float*)d_in[8];
    const float* ar2 = (const float*)d_in[9];
    const float* b2  = (const float*)d_in[10];
    const float* W3  = (const float*)d_in[11];
    const float* al3 = (const float*)d_in[12];
    const float* ar3 = (const float*)d_in[13];
    const float* b3  = (const float*)d_in[14];
    const float* W4  = (const float*)d_in[15];
    const float* al4 = (const float*)d_in[16];
    const float* ar4 = (const float*)d_in[17];
    const float* b4  = (const float*)d_in[18];

    const int* src0 = ei0;            const int* dst0 = ei0 + NEDGE;
    const int* src1 = ei1;            const int* dst1 = ei1 + NEDGE;

    float* out_a = (float*)d_out;                       // h_a  [N,120]
    float* out_f = out_a + (size_t)NNODE * 120;         // h_f  [N,120]

    // ---- workspace layout (floats) ----
    // F0: 2*N*120  (pair1 fc-out hA1/hB1 [N,60] each occupy the front half;
    //               pair2 fc-out hA2/hB2 [N,120] each reuse the full region)
    // F1: 2*N*60   (pair1 aggregated outputs h1, h2)
    // F2: 6*N      (elA, erA, elB, erB, dA, dB)
    float* F0  = (float*)d_ws;
    float* hA1 = F0;
    float* hB1 = F0 + (size_t)NNODE * 60;
    float* hA2 = F0;
    float* hB2 = F0 + (size_t)NNODE * 120;
    float* F1  = F0 + (size_t)2 * NNODE * 120;
    float* h1  = F1;
    float* h2  = F1 + (size_t)NNODE * 60;
    float* F2  = F1 + (size_t)2 * NNODE * 60;
    float* elA = F2;
    float* erA = F2 + NNODE;
    float* elB = F2 + 2 * NNODE;
    float* erB = F2 + 3 * NNODE;
    float* dA  = F2 + 4 * NNODE;
    float* dB  = F2 + 5 * NNODE;

    const int edgeBlocks    = (NEDGE + 255) / 256;
    const int scatterBlocks = NEDGE / 4;   // one 64-lane wave per edge

    // ---------------- pair 1: layers 1 (A) and 3 (B) on edge_index0 --------
    fc_kernel<120, 60><<<NNODE, 128, 0, stream>>>(
        x, x, W1, al1, ar1, W3, al3, ar3, hA1, hB1, elA, erA, elB, erB);
    init_kernel<<<NNODE, 128, 0, stream>>>(h1, b1, h2, b3, 60, dA, dB);
    edge_sum<<<edgeBlocks, 256, 0, stream>>>(src0, dst0, elA, erA, elB, erB, dA, dB);
    edge_scatter<60><<<scatterBlocks, 256, 0, stream>>>(
        src0, dst0, elA, erA, elB, erB, dA, dB, hA1, hB1, h1, h2);

    // ---------------- pair 2: layers 2 (A) and 4 (B) on edge_index1 --------
    fc_kernel<60, 120><<<NNODE, 128, 0, stream>>>(
        h1, h2, W2, al2, ar2, W4, al4, ar4, hA2, hB2, elA, erA, elB, erB);
    init_kernel<<<NNODE, 128, 0, stream>>>(out_a, b2, out_f, b4, 120, dA, dB);
    edge_sum<<<edgeBlocks, 256, 0, stream>>>(src1, dst1, elA, erA, elB, erB, dA, dB);
    edge_scatter<120><<<scatterBlocks, 256, 0, stream>>>(
        src1, dst1, elA, erA, elB, erB, dA, dB, hA2, hB2, out_a, out_f);
}

// Round 2
// 2503.675 us; speedup vs baseline: 2.2653x; 2.2653x over previous
//
#include <hip/hip_runtime.h>

#define NNODE 100000
#define NEDGE 3200000
#define SCAN_NB ((NNODE + 1023) / 1024)   // 98 blocks of 1024 elements

__device__ __forceinline__ float leaky(float x) { return x > 0.f ? x : 0.2f * x; }

// ---------------------------------------------------------------------------
// FC: per node, h = in @ W for two layers (A in wave0, B in wave1), plus
// el = h.al, er = h.ar row reductions. Block = 128 threads = 2 waves.
// ---------------------------------------------------------------------------
template <int DIN, int DOUT>
__global__ __launch_bounds__(128) void fc_kernel(
    const float* __restrict__ inA, const float* __restrict__ inB,
    const float* __restrict__ WA, const float* __restrict__ alA, const float* __restrict__ arA,
    const float* __restrict__ WB, const float* __restrict__ alB, const float* __restrict__ arB,
    float* __restrict__ hA, float* __restrict__ hB,
    float* __restrict__ elA, float* __restrict__ erA,
    float* __restrict__ elB, float* __restrict__ erB)
{
    __shared__ float rowA[DIN], rowB[DIN];
    const int n   = blockIdx.x;
    const int tid = threadIdx.x;
    for (int k = tid; k < DIN; k += 128) {
        rowA[k] = inA[(size_t)n * DIN + k];
        rowB[k] = inB[(size_t)n * DIN + k];
    }
    __syncthreads();

    const int wave = tid >> 6;
    const int lane = tid & 63;
    const float* row = wave ? rowB : rowA;
    const float* W   = wave ? WB : WA;
    const float* al  = wave ? alB : alA;
    const float* ar  = wave ? arB : arA;
    float* h  = wave ? hB : hA;
    float* el = wave ? elB : elA;
    float* er = wave ? erB : erA;

    const int j0 = lane, j1 = lane + 64;
    float acc0 = 0.f, acc1 = 0.f;
#pragma unroll 4
    for (int k = 0; k < DIN; ++k) {
        const float r = row[k];
        const float* Wk = W + k * DOUT;
        if (j0 < DOUT) acc0 += r * Wk[j0];
        if (DOUT > 64) { if (j1 < DOUT) acc1 += r * Wk[j1]; }
    }
    if (j0 < DOUT) h[(size_t)n * DOUT + j0] = acc0;
    if (DOUT > 64) { if (j1 < DOUT) h[(size_t)n * DOUT + j1] = acc1; }

    float cl = 0.f, cr = 0.f;
    if (j0 < DOUT) { cl += acc0 * al[j0]; cr += acc0 * ar[j0]; }
    if (DOUT > 64) { if (j1 < DOUT) { cl += acc1 * al[j1]; cr += acc1 * ar[j1]; } }
#pragma unroll
    for (int off = 32; off > 0; off >>= 1) {
        cl += __shfl_down(cl, off);
        cr += __shfl_down(cr, off);
    }
    if (lane == 0) { el[n] = cl; er[n] = cr; }
}

// ---------------------------------------------------------------------------
// Binning (counting sort by dst): zero -> hist -> 3-kernel exclusive scan ->
// bin-scatter of src ids. All int traffic, L2-resident.
// ---------------------------------------------------------------------------
__global__ __launch_bounds__(256) void zero_counts(int* __restrict__ counts)
{
    const int i = blockIdx.x * 256 + threadIdx.x;
    if (i < NNODE) counts[i] = 0;
}

__global__ __launch_bounds__(256) void hist_kernel(
    const int* __restrict__ dst, int* __restrict__ counts)
{
    for (int e = blockIdx.x * 256 + threadIdx.x; e < NEDGE; e += gridDim.x * 256)
        atomicAdd(&counts[dst[e]], 1);
}

__global__ __launch_bounds__(256) void scan_block_sums(
    const int* __restrict__ counts, int* __restrict__ bsum)
{
    __shared__ int sm[256];
    const int b = blockIdx.x, t = threadIdx.x;
    const int base = b * 1024 + t * 4;
    int s = 0;
#pragma unroll
    for (int k = 0; k < 4; ++k) { int idx = base + k; if (idx < NNODE) s += counts[idx]; }
    sm[t] = s; __syncthreads();
    for (int d = 128; d > 0; d >>= 1) { if (t < d) sm[t] += sm[t + d]; __syncthreads(); }
    if (t == 0) bsum[b] = sm[0];
}

__global__ __launch_bounds__(128) void scan_bsums(
    const int* __restrict__ bsum, int* __restrict__ bscan)
{
    __shared__ int sm[128];
    const int t = threadIdx.x;
    const int v0 = (t < SCAN_NB) ? bsum[t] : 0;
    sm[t] = v0; __syncthreads();
    for (int d = 1; d < 128; d <<= 1) {
        int v = (t >= d) ? sm[t - d] : 0;
        __syncthreads();
        sm[t] += v;
        __syncthreads();
    }
    if (t < SCAN_NB) bscan[t] = sm[t] - v0;   // exclusive
}

__global__ __launch_bounds__(256) void scan_write(
    const int* __restrict__ counts, const int* __restrict__ bscan,
    int* __restrict__ offsets, int* __restrict__ cursor)
{
    __shared__ int sm[256];
    const int b = blockIdx.x, t = threadIdx.x;
    const int base = b * 1024 + t * 4;
    int c[4]; int tot = 0;
#pragma unroll
    for (int k = 0; k < 4; ++k) {
        c[k] = (base + k < NNODE) ? counts[base + k] : 0;
        tot += c[k];
    }
    sm[t] = tot; __syncthreads();
    for (int d = 1; d < 256; d <<= 1) {
        int v = (t >= d) ? sm[t - d] : 0;
        __syncthreads();
        sm[t] += v;
        __syncthreads();
    }
    int run = sm[t] - tot + bscan[b];         // exclusive offset for this thread
#pragma unroll
    for (int k = 0; k < 4; ++k) {
        if (base + k < NNODE) { offsets[base + k] = run; cursor[base + k] = run; run += c[k]; }
    }
    if (b == 0 && t == 0) offsets[NNODE] = NEDGE;
}

__global__ __launch_bounds__(256) void bin_scatter(
    const int* __restrict__ src, const int* __restrict__ dst,
    int* __restrict__ cursor, int* __restrict__ sorted_src)
{
    for (int e = blockIdx.x * 256 + threadIdx.x; e < NEDGE; e += gridDim.x * 256) {
        const int p = atomicAdd(&cursor[dst[e]], 1);
        sorted_src[p] = src[e];
    }
}

// ---------------------------------------------------------------------------
// Gather aggregation: one block (2 waves) per dst node; wave0 layer A,
// wave1 layer B. Walk the dst's contiguous edge segment, accumulate
// num = sum w*h[src] (float4 lanes) and den = sum w in registers; write
// out = num/(den+1e-9) + b exactly once. segment_max skipped (softmax is
// shift-invariant; scores are O(1) -> no f32 overflow risk).
// ---------------------------------------------------------------------------
template <int DOUT>
__global__ __launch_bounds__(128) void aggregate(
    const int* __restrict__ sorted_src, const int* __restrict__ offsets,
    const float* __restrict__ elA, const float* __restrict__ erA,
    const float* __restrict__ elB, const float* __restrict__ erB,
    const float* __restrict__ hA, const float* __restrict__ hB,
    const float* __restrict__ bA, const float* __restrict__ bB,
    float* __restrict__ outA, float* __restrict__ outB)
{
    constexpr int NV = DOUT / 4;           // float4s per row (15 or 30)
    const int n    = blockIdx.x;
    const int wave = threadIdx.x >> 6;
    const int lane = threadIdx.x & 63;

    const float* el = wave ? elB : elA;
    const float  ern = (wave ? erB : erA)[n];
    const float4* h4 = (const float4*)(wave ? hB : hA);
    const float4* b4 = (const float4*)(wave ? bB : bA);
    float4* o4 = (float4*)(wave ? outB : outA);

    const int start = offsets[n];
    const int end   = offsets[n + 1];

    float4 acc = {0.f, 0.f, 0.f, 0.f};
    float den = 0.f;
    const bool act = lane < NV;

    int i = start;
    for (; i + 1 < end; i += 2) {
        const int s0 = sorted_src[i];
        const int s1 = sorted_src[i + 1];
        const float w0 = expf(leaky(el[s0] + ern));
        const float w1 = expf(leaky(el[s1] + ern));
        den += w0 + w1;
        if (act) {
            const float4 v0 = h4[(size_t)s0 * NV + lane];
            const float4 v1 = h4[(size_t)s1 * NV + lane];
            acc.x += w0 * v0.x + w1 * v1.x;
            acc.y += w0 * v0.y + w1 * v1.y;
            acc.z += w0 * v0.z + w1 * v1.z;
            acc.w += w0 * v0.w + w1 * v1.w;
        }
    }
    if (i < end) {
        const int s0 = sorted_src[i];
        const float w0 = expf(leaky(el[s0] + ern));
        den += w0;
        if (act) {
            const float4 v0 = h4[(size_t)s0 * NV + lane];
            acc.x += w0 * v0.x;
            acc.y += w0 * v0.y;
            acc.z += w0 * v0.z;
            acc.w += w0 * v0.w;
        }
    }

    const float inv = 1.f / (den + 1e-9f);
    if (act) {
        const float4 bb = b4[lane];
        float4 o;
        o.x = acc.x * inv + bb.x;
        o.y = acc.y * inv + bb.y;
        o.z = acc.z * inv + bb.z;
        o.w = acc.w * inv + bb.w;
        o4[(size_t)n * NV + lane] = o;
    }
}

// ---------------------------------------------------------------------------
extern "C" void kernel_launch(void* const* d_in, const int* in_sizes, int n_in,
                              void* d_out, int out_size, void* d_ws, size_t ws_size,
                              hipStream_t stream)
{
    const float* x   = (const float*)d_in[0];
    const int* ei0   = (const int*)d_in[1];   // [2,E] int32
    const int* ei1   = (const int*)d_in[2];
    const float* W1  = (const float*)d_in[3];
    const float* al1 = (const float*)d_in[4];
    const float* ar1 = (const float*)d_in[5];
    const float* b1  = (const float*)d_in[6];
    const float* W2  = (const float*)d_in[7];
    const float* al2 = (const float*)d_in[8];
    const float* ar2 = (const float*)d_in[9];
    const float* b2  = (const float*)d_in[10];
    const float* W3  = (const float*)d_in[11];
    const float* al3 = (const float*)d_in[12];
    const float* ar3 = (const float*)d_in[13];
    const float* b3  = (const float*)d_in[14];
    const float* W4  = (const float*)d_in[15];
    const float* al4 = (const float*)d_in[16];
    const float* ar4 = (const float*)d_in[17];
    const float* b4  = (const float*)d_in[18];

    const int* src0 = ei0;  const int* dst0 = ei0 + NEDGE;
    const int* src1 = ei1;  const int* dst1 = ei1 + NEDGE;

    float* out_a = (float*)d_out;                 // final h_a [N,120]
    float* out_f = out_a + (size_t)NNODE * 120;   // final h_f [N,120]
    // pair-1 aggregated outputs live in d_out temporarily (consumed by fc2
    // before the pair-2 aggregate overwrites this region):
    float* h1 = out_a;                            // [N,60]
    float* h2 = out_a + (size_t)NNODE * 60;       // [N,60]

    // ---- workspace layout ----
    float* hA      = (float*)d_ws;                       // [N,120] max
    float* hB      = hA + (size_t)NNODE * 120;           // [N,120] max
    float* elA     = hB + (size_t)NNODE * 120;
    float* erA     = elA + NNODE;
    float* elB     = erA + NNODE;
    float* erB     = elB + NNODE;
    int*   counts  = (int*)(erB + NNODE);                // [N]
    int*   cursor  = counts + NNODE;                     // [N]
    int*   offsets = cursor + NNODE;                     // [N+1]
    int*   bsum    = offsets + NNODE + 1;                // [128]
    int*   bscan   = bsum + 128;                         // [128]
    int*   sorted  = bscan + 128;                        // [E]

    const int zeroBlocks = (NNODE + 255) / 256;
    const int edgeBlocks = 2048;

    // ---------------- pair 1: layers 1 (A) and 3 (B) on edge_index0 --------
    fc_kernel<120, 60><<<NNODE, 128, 0, stream>>>(
        x, x, W1, al1, ar1, W3, al3, ar3, hA, hB, elA, erA, elB, erB);
    zero_counts<<<zeroBlocks, 256, 0, stream>>>(counts);
    hist_kernel<<<edgeBlocks, 256, 0, stream>>>(dst0, counts);
    scan_block_sums<<<SCAN_NB, 256, 0, stream>>>(counts, bsum);
    scan_bsums<<<1, 128, 0, stream>>>(bsum, bscan);
    scan_write<<<SCAN_NB, 256, 0, stream>>>(counts, bscan, offsets, cursor);
    bin_scatter<<<edgeBlocks, 256, 0, stream>>>(src0, dst0, cursor, sorted);
    aggregate<60><<<NNODE, 128, 0, stream>>>(
        sorted, offsets, elA, erA, elB, erB, hA, hB, b1, b3, h1, h2);

    // ---------------- pair 2: layers 2 (A) and 4 (B) on edge_index1 --------
    fc_kernel<60, 120><<<NNODE, 128, 0, stream>>>(
        h1, h2, W2, al2, ar2, W4, al4, ar4, hA, hB, elA, erA, elB, erB);
    zero_counts<<<zeroBlocks, 256, 0, stream>>>(counts);
    hist_kernel<<<edgeBlocks, 256, 0, stream>>>(dst1, counts);
    scan_block_sums<<<SCAN_NB, 256, 0, stream>>>(counts, bsum);
    scan_bsums<<<1, 128, 0, stream>>>(bsum, bscan);
    scan_write<<<SCAN_NB, 256, 0, stream>>>(counts, bscan, offsets, cursor);
    bin_scatter<<<edgeBlocks, 256, 0, stream>>>(src1, dst1, cursor, sorted);
    aggregate<120><<<NNODE, 128, 0, stream>>>(
        sorted, offsets, elA, erA, elB, erB, hA, hB, b2, b4, out_a, out_f);
}

// Round 3
// 1921.966 us; speedup vs baseline: 2.9510x; 1.3027x over previous
//
#include <hip/hip_runtime.h>

#define NNODE 100000
#define NEDGE 3200000
#define BK    256                          // nodes per coarse bucket
#define NB_C  ((NNODE + BK - 1) / BK)      // 391 coarse buckets
#define TILE_E 8192                        // edges per partition tile
#define NTILES ((NEDGE + TILE_E - 1) / TILE_E)  // 391

__device__ __forceinline__ float leaky(float x) { return x > 0.f ? x : 0.2f * x; }

// ---------------------------------------------------------------------------
// FC (pair 1): per node, h = x @ W for layers 1 (wave0) / 3 (wave1) + el/er.
// ---------------------------------------------------------------------------
template <int DIN, int DOUT>
__global__ __launch_bounds__(128) void fc_kernel(
    const float* __restrict__ in,
    const float* __restrict__ WA, const float* __restrict__ alA, const float* __restrict__ arA,
    const float* __restrict__ WB, const float* __restrict__ alB, const float* __restrict__ arB,
    float* __restrict__ hA, float* __restrict__ hB,
    float* __restrict__ elA, float* __restrict__ erA,
    float* __restrict__ elB, float* __restrict__ erB)
{
    __shared__ float row[DIN];
    const int n   = blockIdx.x;
    const int tid = threadIdx.x;
    for (int k = tid; k < DIN; k += 128) row[k] = in[(size_t)n * DIN + k];
    __syncthreads();

    const int wave = tid >> 6;
    const int lane = tid & 63;
    const float* W  = wave ? WB : WA;
    const float* al = wave ? alB : alA;
    const float* ar = wave ? arB : arA;
    float* h  = wave ? hB : hA;
    float* el = wave ? elB : elA;
    float* er = wave ? erB : erA;

    float acc0 = 0.f;
#pragma unroll 4
    for (int k = 0; k < DIN; ++k) {
        const float r = row[k];
        if (lane < DOUT) acc0 += r * W[k * DOUT + lane];
    }
    if (lane < DOUT) h[(size_t)n * DOUT + lane] = acc0;

    float cl = 0.f, cr = 0.f;
    if (lane < DOUT) { cl = acc0 * al[lane]; cr = acc0 * ar[lane]; }
#pragma unroll
    for (int off = 32; off > 0; off >>= 1) {
        cl += __shfl_down(cl, off);
        cr += __shfl_down(cr, off);
    }
    if (lane == 0) { el[n] = cl; er[n] = cr; }
}

// ---------------------------------------------------------------------------
// FC post (pair 2): out = agg @ W + b (wave0: A, wave1: B). DIN=60, DOUT=120.
// ---------------------------------------------------------------------------
__global__ __launch_bounds__(128) void fc_post(
    const float* __restrict__ aggA, const float* __restrict__ aggB,
    const float* __restrict__ WA, const float* __restrict__ bA,
    const float* __restrict__ WB, const float* __restrict__ bB,
    float* __restrict__ outA, float* __restrict__ outB)
{
    __shared__ float rowA[60], rowB[60];
    const int n   = blockIdx.x;
    const int tid = threadIdx.x;
    if (tid < 60)               rowA[tid]      = aggA[(size_t)n * 60 + tid];
    else if (tid < 120)         rowB[tid - 60] = aggB[(size_t)n * 60 + tid - 60];
    __syncthreads();

    const int wave = tid >> 6;
    const int lane = tid & 63;
    const float* row = wave ? rowB : rowA;
    const float* W   = wave ? WB : WA;
    const float* b   = wave ? bB : bA;
    float* out = wave ? outB : outA;

    const int j0 = lane, j1 = lane + 64;
    float acc0 = 0.f, acc1 = 0.f;
#pragma unroll 4
    for (int k = 0; k < 60; ++k) {
        const float r = row[k];
        const float* Wk = W + k * 120;
        acc0 += r * Wk[j0];
        if (j1 < 120) acc1 += r * Wk[j1];
    }
    out[(size_t)n * 120 + j0] = acc0 + b[j0];
    if (j1 < 120) out[(size_t)n * 120 + j1] = acc1 + b[j1];
}

// ---------------------------------------------------------------------------
// prep: vl = W @ al, vr = W @ ar for pair-2 layers (A=W2, B=W4). 1 block.
// ---------------------------------------------------------------------------
__global__ __launch_bounds__(64) void prep_vec(
    const float* __restrict__ W2, const float* __restrict__ al2, const float* __restrict__ ar2,
    const float* __restrict__ W4, const float* __restrict__ al4, const float* __restrict__ ar4,
    float* __restrict__ vlA, float* __restrict__ vrA,
    float* __restrict__ vlB, float* __restrict__ vrB)
{
    const int t = threadIdx.x;
    if (t >= 60) return;
    float a = 0.f, b = 0.f, c = 0.f, d = 0.f;
    for (int j = 0; j < 120; ++j) {
        const float w2 = W2[t * 120 + j];
        const float w4 = W4[t * 120 + j];
        a += w2 * al2[j];  b += w2 * ar2[j];
        c += w4 * al4[j];  d += w4 * ar4[j];
    }
    vlA[t] = a; vrA[t] = b; vlB[t] = c; vrB[t] = d;
}

// ---------------------------------------------------------------------------
// Coarse counting sort: hist -> scan -> partition (packed) -> bucket sort.
// ---------------------------------------------------------------------------
__global__ __launch_bounds__(512) void zero_coarse(int* __restrict__ ccnt)
{
    const int i = threadIdx.x;
    if (i < NB_C) ccnt[i] = 0;
}

__global__ __launch_bounds__(256) void coarse_hist(
    const int* __restrict__ dst, int* __restrict__ ccnt)
{
    __shared__ int lh[NB_C];
    for (int i = threadIdx.x; i < NB_C; i += 256) lh[i] = 0;
    __syncthreads();
    for (int e = blockIdx.x * 256 + threadIdx.x; e < NEDGE; e += gridDim.x * 256)
        atomicAdd(&lh[dst[e] >> 8], 1);
    __syncthreads();
    for (int i = threadIdx.x; i < NB_C; i += 256)
        if (lh[i]) atomicAdd(&ccnt[i], lh[i]);
}

__global__ __launch_bounds__(512) void coarse_scan(
    const int* __restrict__ ccnt, int* __restrict__ coff, int* __restrict__ gcur,
    int* __restrict__ offsets)
{
    __shared__ int sm[512];
    const int t = threadIdx.x;
    const int v = (t < NB_C) ? ccnt[t] : 0;
    sm[t] = v; __syncthreads();
    for (int d = 1; d < 512; d <<= 1) {
        int u = (t >= d) ? sm[t - d] : 0;
        __syncthreads();
        sm[t] += u;
        __syncthreads();
    }
    if (t < NB_C) { const int ex = sm[t] - v; coff[t] = ex; gcur[t] = ex; }
    if (t == NB_C - 1) coff[NB_C] = sm[t];
    if (t == 0) offsets[NNODE] = NEDGE;
}

// pass 1: partition edges into coarse buckets, packed = (dst&255)<<17 | src
__global__ __launch_bounds__(256) void partition_kernel(
    const int* __restrict__ src, const int* __restrict__ dst,
    int* __restrict__ gcur, unsigned* __restrict__ packed)
{
    __shared__ int lh[NB_C];
    __shared__ int lcur[NB_C];
    const int t    = threadIdx.x;
    const int base = blockIdx.x * TILE_E;

    for (int i = t; i < NB_C; i += 256) lh[i] = 0;
    __syncthreads();
#pragma unroll
    for (int k = 0; k < TILE_E / 256; ++k) {
        const int e = base + k * 256 + t;
        if (e < NEDGE) atomicAdd(&lh[dst[e] >> 8], 1);
    }
    __syncthreads();
    for (int i = t; i < NB_C; i += 256) {
        const int c = lh[i];
        lcur[i] = c ? atomicAdd(&gcur[i], c) : 0;
    }
    __syncthreads();
#pragma unroll
    for (int k = 0; k < TILE_E / 256; ++k) {
        const int e = base + k * 256 + t;
        if (e < NEDGE) {
            const int d = dst[e];
            const int pos = atomicAdd(&lcur[d >> 8], 1);
            packed[pos] = ((unsigned)(d & 255) << 17) | (unsigned)src[e];
        }
    }
}

// pass 2: within each bucket, node-level sort + write per-node offsets
__global__ __launch_bounds__(256) void bucket_sort(
    const unsigned* __restrict__ packed, const int* __restrict__ coff,
    int* __restrict__ offsets, int* __restrict__ sorted)
{
    __shared__ int cnt[256];
    __shared__ int sm[256];
    __shared__ int cur[256];
    const int b   = blockIdx.x;
    const int t   = threadIdx.x;
    const int beg = coff[b];
    const int end = coff[b + 1];
    const int node_base = b * BK;

    cnt[t] = 0; __syncthreads();
    for (int i = beg + t; i < end; i += 256)
        atomicAdd(&cnt[packed[i] >> 17], 1);
    __syncthreads();
    const int v = cnt[t];
    sm[t] = v; __syncthreads();
    for (int d = 1; d < 256; d <<= 1) {
        int u = (t >= d) ? sm[t - d] : 0;
        __syncthreads();
        sm[t] += u;
        __syncthreads();
    }
    const int off_n = beg + sm[t] - v;      // exclusive
    if (node_base + t < NNODE) offsets[node_base + t] = off_n;
    cur[t] = off_n;
    __syncthreads();
    for (int i = beg + t; i < end; i += 256) {
        const unsigned p = packed[i];
        const int pos = atomicAdd(&cur[p >> 17], 1);
        sorted[pos] = (int)(p & 0x1FFFFu);
    }
}

// ---------------------------------------------------------------------------
// Aggregate (60-wide rows): out[n] = (sum_e w_e * h[src_e]) / (sum w + 1e-9)
// (+ optional bias). FUSED variant also computes pair-2 el/er by dotting the
// output row with precomputed vl/vr. segment_max skipped (softmax is
// shift-invariant; scores O(1) => no f32 overflow).
// ---------------------------------------------------------------------------
template <bool FUSED>
__global__ __launch_bounds__(128) void aggregate60(
    const int* __restrict__ sorted_src, const int* __restrict__ offsets,
    const float* __restrict__ elA, const float* __restrict__ erA,
    const float* __restrict__ elB, const float* __restrict__ erB,
    const float* __restrict__ hA, const float* __restrict__ hB,
    const float* __restrict__ bA, const float* __restrict__ bB,   // may be null
    const float* __restrict__ vlA, const float* __restrict__ vrA,
    const float* __restrict__ vlB, const float* __restrict__ vrB,
    float* __restrict__ outA, float* __restrict__ outB,
    float* __restrict__ el2A, float* __restrict__ er2A,
    float* __restrict__ el2B, float* __restrict__ er2B)
{
    constexpr int NV = 15;                 // float4s per 60-wide row
    const int n    = blockIdx.x;
    const int wave = threadIdx.x >> 6;
    const int lane = threadIdx.x & 63;

    const float* el  = wave ? elB : elA;
    const float  ern = (wave ? erB : erA)[n];
    const float4* h4 = (const float4*)(wave ? hB : hA);
    float4* o4 = (float4*)(wave ? outB : outA);

    const int start = offsets[n];
    const int end   = offsets[n + 1];

    float4 acc = {0.f, 0.f, 0.f, 0.f};
    float den = 0.f;
    const bool act = lane < NV;

    int i = start;
    for (; i + 1 < end; i += 2) {
        const int s0 = sorted_src[i];
        const int s1 = sorted_src[i + 1];
        const float w0 = expf(leaky(el[s0] + ern));
        const float w1 = expf(leaky(el[s1] + ern));
        den += w0 + w1;
        if (act) {
            const float4 v0 = h4[(size_t)s0 * NV + lane];
            const float4 v1 = h4[(size_t)s1 * NV + lane];
            acc.x += w0 * v0.x + w1 * v1.x;
            acc.y += w0 * v0.y + w1 * v1.y;
            acc.z += w0 * v0.z + w1 * v1.z;
            acc.w += w0 * v0.w + w1 * v1.w;
        }
    }
    if (i < end) {
        const int s0 = sorted_src[i];
        const float w0 = expf(leaky(el[s0] + ern));
        den += w0;
        if (act) {
            const float4 v0 = h4[(size_t)s0 * NV + lane];
            acc.x += w0 * v0.x;
            acc.y += w0 * v0.y;
            acc.z += w0 * v0.z;
            acc.w += w0 * v0.w;
        }
    }

    const float inv = 1.f / (den + 1e-9f);
    float4 o = {0.f, 0.f, 0.f, 0.f};
    if (act) {
        o.x = acc.x * inv;
        o.y = acc.y * inv;
        o.z = acc.z * inv;
        o.w = acc.w * inv;
        if (FUSED) {
            const float4 bb = ((const float4*)(wave ? bB : bA))[lane];
            o.x += bb.x; o.y += bb.y; o.z += bb.z; o.w += bb.w;
        }
        o4[(size_t)n * NV + lane] = o;
    }

    if (FUSED) {
        const float4* vl4 = (const float4*)(wave ? vlB : vlA);
        const float4* vr4 = (const float4*)(wave ? vrB : vrA);
        float pl = 0.f, pr = 0.f;
        if (act) {
            const float4 l = vl4[lane], r = vr4[lane];
            pl = o.x * l.x + o.y * l.y + o.z * l.z + o.w * l.w;
            pr = o.x * r.x + o.y * r.y + o.z * r.z + o.w * r.w;
        }
#pragma unroll
        for (int off = 32; off > 0; off >>= 1) {
            pl += __shfl_down(pl, off);
            pr += __shfl_down(pr, off);
        }
        if (lane == 0) {
            if (wave) { el2B[n] = pl; er2B[n] = pr; }
            else      { el2A[n] = pl; er2A[n] = pr; }
        }
    }
}

// ---------------------------------------------------------------------------
extern "C" void kernel_launch(void* const* d_in, const int* in_sizes, int n_in,
                              void* d_out, int out_size, void* d_ws, size_t ws_size,
                              hipStream_t stream)
{
    const float* x   = (const float*)d_in[0];
    const int* ei0   = (const int*)d_in[1];
    const int* ei1   = (const int*)d_in[2];
    const float* W1  = (const float*)d_in[3];
    const float* al1 = (const float*)d_in[4];
    const float* ar1 = (const float*)d_in[5];
    const float* b1  = (const float*)d_in[6];
    const float* W2  = (const float*)d_in[7];
    const float* al2 = (const float*)d_in[8];
    const float* ar2 = (const float*)d_in[9];
    const float* b2  = (const float*)d_in[10];
    const float* W3  = (const float*)d_in[11];
    const float* al3 = (const float*)d_in[12];
    const float* ar3 = (const float*)d_in[13];
    const float* b3  = (const float*)d_in[14];
    const float* W4  = (const float*)d_in[15];
    const float* al4 = (const float*)d_in[16];
    const float* ar4 = (const float*)d_in[17];
    const float* b4  = (const float*)d_in[18];

    const int* src0 = ei0;  const int* dst0 = ei0 + NEDGE;
    const int* src1 = ei1;  const int* dst1 = ei1 + NEDGE;

    float* out_a = (float*)d_out;                 // final h_a [N,120]
    float* out_f = out_a + (size_t)NNODE * 120;   // final h_f [N,120]
    float* h1 = out_a;                            // pair-1 agg out [N,60] (temp)
    float* h2 = out_a + (size_t)NNODE * 60;       // pair-1 agg out [N,60] (temp)

    // ---- workspace layout ----
    float* hA    = (float*)d_ws;                  // [N,60] fc1-A; later aggA
    float* hB    = hA + (size_t)NNODE * 60;       // [N,60] fc1-B; later aggB
    float* el1A  = hB + (size_t)NNODE * 60;
    float* er1A  = el1A + NNODE;
    float* el1B  = er1A + NNODE;
    float* er1B  = el1B + NNODE;
    float* el2A  = er1B + NNODE;
    float* er2A  = el2A + NNODE;
    float* el2B  = er2A + NNODE;
    float* er2B  = el2B + NNODE;
    float* vlA   = er2B + NNODE;                  // 60 each, float4-aligned
    float* vrA   = vlA + 60;
    float* vlB   = vrA + 60;
    float* vrB   = vlB + 60;
    int*   ccnt    = (int*)(vrB + 60);            // [NB_C]
    int*   coff    = ccnt + NB_C;                 // [NB_C+1]
    int*   gcur    = coff + NB_C + 1;             // [NB_C]
    int*   offsets = gcur + NB_C;                 // [N+1]
    unsigned* packed = (unsigned*)(offsets + NNODE + 1);  // [E]
    int*   sorted  = (int*)(packed + NEDGE);      // [E]

    // ---------------- pair 1: layers 1 (A) / 3 (B) on edge_index0 ----------
    prep_vec<<<1, 64, 0, stream>>>(W2, al2, ar2, W4, al4, ar4, vlA, vrA, vlB, vrB);
    fc_kernel<120, 60><<<NNODE, 128, 0, stream>>>(
        x, W1, al1, ar1, W3, al3, ar3, hA, hB, el1A, er1A, el1B, er1B);
    zero_coarse<<<1, 512, 0, stream>>>(ccnt);
    coarse_hist<<<256, 256, 0, stream>>>(dst0, ccnt);
    coarse_scan<<<1, 512, 0, stream>>>(ccnt, coff, gcur, offsets);
    partition_kernel<<<NTILES, 256, 0, stream>>>(src0, dst0, gcur, packed);
    bucket_sort<<<NB_C, 256, 0, stream>>>(packed, coff, offsets, sorted);
    aggregate60<true><<<NNODE, 128, 0, stream>>>(
        sorted, offsets, el1A, er1A, el1B, er1B, hA, hB, b1, b3,
        vlA, vrA, vlB, vrB, h1, h2, el2A, er2A, el2B, er2B);

    // ---------------- pair 2: layers 2 (A) / 4 (B) on edge_index1 ----------
    zero_coarse<<<1, 512, 0, stream>>>(ccnt);
    coarse_hist<<<256, 256, 0, stream>>>(dst1, ccnt);
    coarse_scan<<<1, 512, 0, stream>>>(ccnt, coff, gcur, offsets);
    partition_kernel<<<NTILES, 256, 0, stream>>>(src1, dst1, gcur, packed);
    bucket_sort<<<NB_C, 256, 0, stream>>>(packed, coff, offsets, sorted);
    // aggregate inputs h1/h2 (60-wide) with pair-2 attention weights; apply
    // W after aggregation (linearity: sum(alpha * (h@W)) = (sum(alpha*h))@W).
    aggregate60<false><<<NNODE, 128, 0, stream>>>(
        sorted, offsets, el2A, er2A, el2B, er2B, h1, h2, nullptr, nullptr,
        nullptr, nullptr, nullptr, nullptr, hA, hB,
        nullptr, nullptr, nullptr, nullptr);
    fc_post<<<NNODE, 128, 0, stream>>>(hA, hB, W2, b2, W4, b4, out_a, out_f);
}

// Round 11
// 1795.243 us; speedup vs baseline: 3.1593x; 1.0706x over previous
//
#include <hip/hip_runtime.h>

#define NNODE 100000
#define NEDGE 3200000
#define BK    256                          // nodes per coarse bucket
#define NB_C  ((NNODE + BK - 1) / BK)      // 391 coarse buckets
#define TILE_E 8192                        // edges per partition tile
#define NTILES ((NEDGE + TILE_E - 1) / TILE_E)  // 391

__device__ __forceinline__ float leaky(float x) { return x > 0.f ? x : 0.2f * x; }

__device__ __forceinline__ float wave_sum64(float v) {
#pragma unroll
    for (int off = 32; off > 0; off >>= 1) v += __shfl_down(v, off);
    return v;   // valid in lane 0
}

// ---------------------------------------------------------------------------
// FC1: 8 nodes/block, 256 thr = 4 waves. wave w: layer = w>>1 (A/B),
// nodes (w&1)*4 .. +3. x rows staged as float4 in LDS; 1 W load feeds 4 FMAs.
// h output padded to 64 floats/row (lanes 60-63 naturally accumulate 0).
// ---------------------------------------------------------------------------
__global__ __launch_bounds__(256) void fc1_kernel(
    const float* __restrict__ x,
    const float* __restrict__ WA, const float* __restrict__ alA, const float* __restrict__ arA,
    const float* __restrict__ WB, const float* __restrict__ alB, const float* __restrict__ arB,
    float* __restrict__ hA, float* __restrict__ hB,
    float* __restrict__ elA, float* __restrict__ erA,
    float* __restrict__ elB, float* __restrict__ erB)
{
    __shared__ float4 rows[8][30];         // 8 nodes x 120 floats
    const int base = blockIdx.x * 8;
    const int tid  = threadIdx.x;
    const float4* x4 = (const float4*)(x + (size_t)base * 120);
    if (tid < 240) rows[tid / 30][tid % 30] = x4[tid];
    __syncthreads();

    const int wave  = tid >> 6;
    const int lane  = tid & 63;
    const int layer = wave >> 1;
    const int nd    = (wave & 1) * 4;
    const float* W  = layer ? WB : WA;
    const float* al = layer ? alB : alA;
    const float* ar = layer ? arB : arA;
    float* h  = layer ? hB : hA;
    float* el = layer ? elB : elA;
    float* er = layer ? erB : erA;

    const bool act = lane < 60;
    float a0 = 0.f, a1 = 0.f, a2 = 0.f, a3 = 0.f;
#pragma unroll
    for (int kq = 0; kq < 30; ++kq) {
        const float4 r0 = rows[nd + 0][kq];
        const float4 r1 = rows[nd + 1][kq];
        const float4 r2 = rows[nd + 2][kq];
        const float4 r3 = rows[nd + 3][kq];
        const int k = kq * 4;
        const float w0 = act ? W[(k + 0) * 60 + lane] : 0.f;
        const float w1 = act ? W[(k + 1) * 60 + lane] : 0.f;
        const float w2 = act ? W[(k + 2) * 60 + lane] : 0.f;
        const float w3 = act ? W[(k + 3) * 60 + lane] : 0.f;
        a0 += r0.x * w0 + r0.y * w1 + r0.z * w2 + r0.w * w3;
        a1 += r1.x * w0 + r1.y * w1 + r1.z * w2 + r1.w * w3;
        a2 += r2.x * w0 + r2.y * w1 + r2.z * w2 + r2.w * w3;
        a3 += r3.x * w0 + r3.y * w1 + r3.z * w2 + r3.w * w3;
    }

    // store padded rows (lanes 60-63 hold 0)
    h[(size_t)(base + nd + 0) * 64 + lane] = a0;
    h[(size_t)(base + nd + 1) * 64 + lane] = a1;
    h[(size_t)(base + nd + 2) * 64 + lane] = a2;
    h[(size_t)(base + nd + 3) * 64 + lane] = a3;

    const int wj = act ? lane : 59;        // a_i = 0 for lanes >= 60
    const float alv = al[wj], arv = ar[wj];
    float cl, cr;
    cl = wave_sum64(a0 * alv); cr = wave_sum64(a0 * arv);
    if (lane == 0) { el[base + nd + 0] = cl; er[base + nd + 0] = cr; }
    cl = wave_sum64(a1 * alv); cr = wave_sum64(a1 * arv);
    if (lane == 0) { el[base + nd + 1] = cl; er[base + nd + 1] = cr; }
    cl = wave_sum64(a2 * alv); cr = wave_sum64(a2 * arv);
    if (lane == 0) { el[base + nd + 2] = cl; er[base + nd + 2] = cr; }
    cl = wave_sum64(a3 * alv); cr = wave_sum64(a3 * arv);
    if (lane == 0) { el[base + nd + 3] = cl; er[base + nd + 3] = cr; }
}

// ---------------------------------------------------------------------------
// FC post: 4 nodes/block, 4 waves; wave: layer = w>>1, nodes (w&1)*2 .. +1.
// DIN=60 (rows padded 64), DOUT=120 (j0=lane, j1=lane+64 for lane<56).
// ---------------------------------------------------------------------------
__global__ __launch_bounds__(256) void fc_post(
    const float* __restrict__ aggA, const float* __restrict__ aggB,  // [N,64]
    const float* __restrict__ WA, const float* __restrict__ bA,
    const float* __restrict__ WB, const float* __restrict__ bB,
    float* __restrict__ outA, float* __restrict__ outB)              // [N,120]
{
    __shared__ float4 rows[2][4][16];
    const int base = blockIdx.x * 4;
    const int tid  = threadIdx.x;
    if (tid < 128) {
        const int l = tid >> 6, r = (tid >> 4) & 3, q = tid & 15;
        const float4* srcp = (const float4*)((l ? aggB : aggA) + (size_t)(base + r) * 64);
        rows[l][r][q] = srcp[q];
    }
    __syncthreads();

    const int wave  = tid >> 6;
    const int lane  = tid & 63;
    const int layer = wave >> 1;
    const int nd    = (wave & 1) * 2;
    const float* W = layer ? WB : WA;
    const float* b = layer ? bB : bA;
    float* out = layer ? outB : outA;

    const int j0 = lane, j1 = lane + 64;
    const bool hi = lane < 56;             // j1 < 120
    float a00 = 0.f, a01 = 0.f, a10 = 0.f, a11 = 0.f;
#pragma unroll
    for (int kq = 0; kq < 15; ++kq) {      // k < 60 (skip pad quad)
        const float4 r0 = rows[layer][nd + 0][kq];
        const float4 r1 = rows[layer][nd + 1][kq];
        const int k = kq * 4;
        const float wa0 = W[(k + 0) * 120 + j0];
        const float wa1 = W[(k + 1) * 120 + j0];
        const float wa2 = W[(k + 2) * 120 + j0];
        const float wa3 = W[(k + 3) * 120 + j0];
        a00 += r0.x * wa0 + r0.y * wa1 + r0.z * wa2 + r0.w * wa3;
        a10 += r1.x * wa0 + r1.y * wa1 + r1.z * wa2 + r1.w * wa3;
        if (hi) {
            const float wb0 = W[(k + 0) * 120 + j1];
            const float wb1 = W[(k + 1) * 120 + j1];
            const float wb2 = W[(k + 2) * 120 + j1];
            const float wb3 = W[(k + 3) * 120 + j1];
            a01 += r0.x * wb0 + r0.y * wb1 + r0.z * wb2 + r0.w * wb3;
            a11 += r1.x * wb0 + r1.y * wb1 + r1.z * wb2 + r1.w * wb3;
        }
    }
    const size_t n0 = base + nd + 0, n1 = base + nd + 1;
    out[n0 * 120 + j0] = a00 + b[j0];
    out[n1 * 120 + j0] = a10 + b[j0];
    if (hi) {
        out[n0 * 120 + j1] = a01 + b[j1];
        out[n1 * 120 + j1] = a11 + b[j1];
    }
}

// ---------------------------------------------------------------------------
// prep: vl = W @ al, vr = W @ ar for pair-2 layers, padded to 64 with zeros.
// ---------------------------------------------------------------------------
__global__ __launch_bounds__(64) void prep_vec(
    const float* __restrict__ W2, const float* __restrict__ al2, const float* __restrict__ ar2,
    const float* __restrict__ W4, const float* __restrict__ al4, const float* __restrict__ ar4,
    float* __restrict__ vlA, float* __restrict__ vrA,
    float* __restrict__ vlB, float* __restrict__ vrB)
{
    const int t = threadIdx.x;
    float a = 0.f, b = 0.f, c = 0.f, d = 0.f;
    if (t < 60) {
        for (int j = 0; j < 120; ++j) {
            const float w2 = W2[t * 120 + j];
            const float w4 = W4[t * 120 + j];
            a += w2 * al2[j];  b += w2 * ar2[j];
            c += w4 * al4[j];  d += w4 * ar4[j];
        }
    }
    vlA[t] = a; vrA[t] = b; vlB[t] = c; vrB[t] = d;
}

// ---------------------------------------------------------------------------
// Coarse counting sort: hist -> scan -> partition (packed) -> bucket sort.
// ---------------------------------------------------------------------------
__global__ __launch_bounds__(512) void zero_coarse(int* __restrict__ ccnt)
{
    const int i = threadIdx.x;
    if (i < NB_C) ccnt[i] = 0;
}

__global__ __launch_bounds__(256) void coarse_hist(
    const int* __restrict__ dst, int* __restrict__ ccnt)
{
    __shared__ int lh[NB_C];
    for (int i = threadIdx.x; i < NB_C; i += 256) lh[i] = 0;
    __syncthreads();
    for (int e = blockIdx.x * 256 + threadIdx.x; e < NEDGE; e += gridDim.x * 256)
        atomicAdd(&lh[dst[e] >> 8], 1);
    __syncthreads();
    for (int i = threadIdx.x; i < NB_C; i += 256)
        if (lh[i]) atomicAdd(&ccnt[i], lh[i]);
}

__global__ __launch_bounds__(512) void coarse_scan(
    const int* __restrict__ ccnt, int* __restrict__ coff, int* __restrict__ gcur,
    int* __restrict__ offsets)
{
    __shared__ int sm[512];
    const int t = threadIdx.x;
    const int v = (t < NB_C) ? ccnt[t] : 0;
    sm[t] = v; __syncthreads();
    for (int d = 1; d < 512; d <<= 1) {
        int u = (t >= d) ? sm[t - d] : 0;
        __syncthreads();
        sm[t] += u;
        __syncthreads();
    }
    if (t < NB_C) { const int ex = sm[t] - v; coff[t] = ex; gcur[t] = ex; }
    if (t == NB_C - 1) coff[NB_C] = sm[t];
    if (t == 0) offsets[NNODE] = NEDGE;
}

__global__ __launch_bounds__(256) void partition_kernel(
    const int* __restrict__ src, const int* __restrict__ dst,
    int* __restrict__ gcur, unsigned* __restrict__ packed)
{
    __shared__ int lh[NB_C];
    __shared__ int lcur[NB_C];
    const int t    = threadIdx.x;
    const int base = blockIdx.x * TILE_E;

    for (int i = t; i < NB_C; i += 256) lh[i] = 0;
    __syncthreads();
#pragma unroll
    for (int k = 0; k < TILE_E / 256; ++k) {
        const int e = base + k * 256 + t;
        if (e < NEDGE) atomicAdd(&lh[dst[e] >> 8], 1);
    }
    __syncthreads();
    for (int i = t; i < NB_C; i += 256) {
        const int c = lh[i];
        lcur[i] = c ? atomicAdd(&gcur[i], c) : 0;
    }
    __syncthreads();
#pragma unroll
    for (int k = 0; k < TILE_E / 256; ++k) {
        const int e = base + k * 256 + t;
        if (e < NEDGE) {
            const int d = dst[e];
            const int pos = atomicAdd(&lcur[d >> 8], 1);
            packed[pos] = ((unsigned)(d & 255) << 17) | (unsigned)src[e];
        }
    }
}

__global__ __launch_bounds__(256) void bucket_sort(
    const unsigned* __restrict__ packed, const int* __restrict__ coff,
    int* __restrict__ offsets, int* __restrict__ sorted)
{
    __shared__ int cnt[256];
    __shared__ int sm[256];
    __shared__ int cur[256];
    const int b   = blockIdx.x;
    const int t   = threadIdx.x;
    const int beg = coff[b];
    const int end = coff[b + 1];
    const int node_base = b * BK;

    cnt[t] = 0; __syncthreads();
    for (int i = beg + t; i < end; i += 256)
        atomicAdd(&cnt[packed[i] >> 17], 1);
    __syncthreads();
    const int v = cnt[t];
    sm[t] = v; __syncthreads();
    for (int d = 1; d < 256; d <<= 1) {
        int u = (t >= d) ? sm[t - d] : 0;
        __syncthreads();
        sm[t] += u;
        __syncthreads();
    }
    const int off_n = beg + sm[t] - v;
    if (node_base + t < NNODE) offsets[node_base + t] = off_n;
    cur[t] = off_n;
    __syncthreads();
    for (int i = beg + t; i < end; i += 256) {
        const unsigned p = packed[i];
        const int pos = atomicAdd(&cur[p >> 17], 1);
        sorted[pos] = (int)(p & 0x1FFFFu);
    }
}

// ---------------------------------------------------------------------------
// Aggregate over padded [N,64] rows, 4 edges per wave-iteration.
// Lanes: group g = lane>>4 handles edge i+g; j = lane&15 indexes the row's
// 16 float4s. Group partials folded with shfl_xor(16/32). wave0=A, wave1=B.
// FUSED: adds bias and computes pair-2 el/er = dot(out, vl/vr).
// segment_max skipped (softmax shift-invariant; scores O(1), no overflow).
// ---------------------------------------------------------------------------
template <bool FUSED>
__global__ __launch_bounds__(128) void aggregate64(
    const int* __restrict__ sorted_src, const int* __restrict__ offsets,
    const float* __restrict__ elA, const float* __restrict__ erA,
    const float* __restrict__ elB, const float* __restrict__ erB,
    const float* __restrict__ hA, const float* __restrict__ hB,   // [N,64]
    const float* __restrict__ bA, const float* __restrict__ bB,
    const float* __restrict__ vlA, const float* __restrict__ vrA, // [64] padded
    const float* __restrict__ vlB, const float* __restrict__ vrB,
    float* __restrict__ outA, float* __restrict__ outB,           // [N,64]
    float* __restrict__ el2A, float* __restrict__ er2A,
    float* __restrict__ el2B, float* __restrict__ er2B)
{
    const int n    = blockIdx.x;
    const int wave = threadIdx.x >> 6;
    const int lane = threadIdx.x & 63;
    const int g    = lane >> 4;
    const int j    = lane & 15;

    const float* el  = wave ? elB : elA;
    const float  ern = (wave ? erB : erA)[n];
    const float4* h4 = (const float4*)(wave ? hB : hA);
    float4* o4 = (float4*)(wave ? outB : outA);

    const int start = offsets[n];
    const int end   = offsets[n + 1];

    float4 acc = {0.f, 0.f, 0.f, 0.f};
    float den = 0.f;

    for (int i = start; i < end; i += 8) {
        const int i0 = i + g, i1 = i + 4 + g;
        const int c0 = min(i0, end - 1), c1 = min(i1, end - 1);
        const int s0 = sorted_src[c0];
        const int s1 = sorted_src[c1];
        const float w0 = (i0 < end) ? expf(leaky(el[s0] + ern)) : 0.f;
        const float w1 = (i1 < end) ? expf(leaky(el[s1] + ern)) : 0.f;
        const float4 v0 = h4[(size_t)s0 * 16 + j];
        const float4 v1 = h4[(size_t)s1 * 16 + j];
        den += w0 + w1;
        acc.x += w0 * v0.x + w1 * v1.x;
        acc.y += w0 * v0.y + w1 * v1.y;
        acc.z += w0 * v0.z + w1 * v1.z;
        acc.w += w0 * v0.w + w1 * v1.w;
    }

    // fold the 4 edge-groups
    den   += __shfl_xor(den, 16);   den   += __shfl_xor(den, 32);
    acc.x += __shfl_xor(acc.x, 16); acc.x += __shfl_xor(acc.x, 32);
    acc.y += __shfl_xor(acc.y, 16); acc.y += __shfl_xor(acc.y, 32);
    acc.z += __shfl_xor(acc.z, 16); acc.z += __shfl_xor(acc.z, 32);
    acc.w += __shfl_xor(acc.w, 16); acc.w += __shfl_xor(acc.w, 32);

    const float inv = 1.f / (den + 1e-9f);
    float4 o;
    o.x = acc.x * inv; o.y = acc.y * inv; o.z = acc.z * inv; o.w = acc.w * inv;
    if (FUSED) {
        if (j < 15) {       // bias has exactly 15 float4s; pad quad = 0
            const float4 bb = ((const float4*)(wave ? bB : bA))[j];
            o.x += bb.x; o.y += bb.y; o.z += bb.z; o.w += bb.w;
        }
    }
    if (g == 0) o4[(size_t)n * 16 + j] = o;

    if (FUSED) {
        const float4* vl4 = (const float4*)(wave ? vlB : vlA);
        const float4* vr4 = (const float4*)(wave ? vrB : vrA);
        const float4 l = vl4[j], r = vr4[j];
        float pl = o.x * l.x + o.y * l.y + o.z * l.z + o.w * l.w;
        float pr = o.x * r.x + o.y * r.y + o.z * r.z + o.w * r.w;
#pragma unroll
        for (int off = 1; off < 16; off <<= 1) {
            pl += __shfl_xor(pl, off);
            pr += __shfl_xor(pr, off);
        }
        if (lane == 0) {
            if (wave) { el2B[n] = pl; er2B[n] = pr; }
            else      { el2A[n] = pl; er2A[n] = pr; }
        }
    }
}

// ---------------------------------------------------------------------------
extern "C" void kernel_launch(void* const* d_in, const int* in_sizes, int n_in,
                              void* d_out, int out_size, void* d_ws, size_t ws_size,
                              hipStream_t stream)
{
    const float* x   = (const float*)d_in[0];
    const int* ei0   = (const int*)d_in[1];
    const int* ei1   = (const int*)d_in[2];
    const float* W1  = (const float*)d_in[3];
    const float* al1 = (const float*)d_in[4];
    const float* ar1 = (const float*)d_in[5];
    const float* b1  = (const float*)d_in[6];
    const float* W2  = (const float*)d_in[7];
    const float* al2 = (const float*)d_in[8];
    const float* ar2 = (const float*)d_in[9];
    const float* b2  = (const float*)d_in[10];
    const float* W3  = (const float*)d_in[11];
    const float* al3 = (const float*)d_in[12];
    const float* ar3 = (const float*)d_in[13];
    const float* b3  = (const float*)d_in[14];
    const float* W4  = (const float*)d_in[15];
    const float* al4 = (const float*)d_in[16];
    const float* ar4 = (const float*)d_in[17];
    const float* b4  = (const float*)d_in[18];

    const int* src0 = ei0;  const int* dst0 = ei0 + NEDGE;
    const int* src1 = ei1;  const int* dst1 = ei1 + NEDGE;

    float* out_a = (float*)d_out;                 // final h_a [N,120]
    float* out_f = out_a + (size_t)NNODE * 120;   // final h_f [N,120]
    // pair-1 aggregated outputs (padded [N,64]) live in d_out temporarily;
    // consumed by pair-2 aggregate before fc_post overwrites the region.
    float* h1 = out_a;                            // [N,64]
    float* h2 = out_a + (size_t)NNODE * 64;       // [N,64]

    // ---- workspace layout (floats, all offsets 16B-aligned) ----
    float* hA    = (float*)d_ws;                  // [N,64] fc1-A; later pair-2 agg A
    float* hB    = hA + (size_t)NNODE * 64;       // [N,64] fc1-B; later pair-2 agg B
    float* el1A  = hB + (size_t)NNODE * 64;
    float* er1A  = el1A + NNODE;
    float* el1B  = er1A + NNODE;
    float* er1B  = el1B + NNODE;
    float* el2A  = er1B + NNODE;
    float* er2A  = el2A + NNODE;
    float* el2B  = er2A + NNODE;
    float* er2B  = el2B + NNODE;
    float* vlA   = er2B + NNODE;                  // [64] padded
    float* vrA   = vlA + 64;
    float* vlB   = vrA + 64;
    float* vrB   = vlB + 64;
    int*   ccnt    = (int*)(vrB + 64);            // [NB_C]
    int*   coff    = ccnt + NB_C;                 // [NB_C+1]
    int*   gcur    = coff + NB_C + 1;             // [NB_C]
    int*   offsets = gcur + NB_C;                 // [N+1]
    unsigned* packed = (unsigned*)(offsets + NNODE + 1);  // [E]
    int*   sorted  = (int*)(packed + NEDGE);      // [E]

    // ---------------- pair 1: layers 1 (A) / 3 (B) on edge_index0 ----------
    prep_vec<<<1, 64, 0, stream>>>(W2, al2, ar2, W4, al4, ar4, vlA, vrA, vlB, vrB);
    fc1_kernel<<<NNODE / 8, 256, 0, stream>>>(
        x, W1, al1, ar1, W3, al3, ar3, hA, hB, el1A, er1A, el1B, er1B);
    zero_coarse<<<1, 512, 0, stream>>>(ccnt);
    coarse_hist<<<256, 256, 0, stream>>>(dst0, ccnt);
    coarse_scan<<<1, 512, 0, stream>>>(ccnt, coff, gcur, offsets);
    partition_kernel<<<NTILES, 256, 0, stream>>>(src0, dst0, gcur, packed);
    bucket_sort<<<NB_C, 256, 0, stream>>>(packed, coff, offsets, sorted);
    aggregate64<true><<<NNODE, 128, 0, stream>>>(
        sorted, offsets, el1A, er1A, el1B, er1B, hA, hB, b1, b3,
        vlA, vrA, vlB, vrB, h1, h2, el2A, er2A, el2B, er2B);

    // ---------------- pair 2: layers 2 (A) / 4 (B) on edge_index1 ----------
    zero_coarse<<<1, 512, 0, stream>>>(ccnt);
    coarse_hist<<<256, 256, 0, stream>>>(dst1, ccnt);
    coarse_scan<<<1, 512, 0, stream>>>(ccnt, coff, gcur, offsets);
    partition_kernel<<<NTILES, 256, 0, stream>>>(src1, dst1, gcur, packed);
    bucket_sort<<<NB_C, 256, 0, stream>>>(packed, coff, offsets, sorted);
    // aggregate 60-wide (padded 64) inputs h1/h2 with pair-2 attention
    // weights; W applied after aggregation (linearity).
    aggregate64<false><<<NNODE, 128, 0, stream>>>(
        sorted, offsets, el2A, er2A, el2B, er2B, h1, h2, nullptr, nullptr,
        nullptr, nullptr, nullptr, nullptr, hA, hB,
        nullptr, nullptr, nullptr, nullptr);
    fc_post<<<NNODE / 4, 256, 0, stream>>>(hA, hB, W2, b2, W4, b4, out_a, out_f);
}

// Round 13
// 1118.579 us; speedup vs baseline: 5.0704x; 1.6049x over previous
//
#include <hip/hip_runtime.h>

#define NNODE 100000
#define NEDGE 3200000
#define BK    256                          // nodes per coarse bucket
#define NB_C  ((NNODE + BK - 1) / BK)      // 391 coarse buckets
#define TILE_E 8192                        // edges per partition tile
#define NTILES ((NEDGE + TILE_E - 1) / TILE_E)  // 391

__device__ __forceinline__ float leaky(float x) { return x > 0.f ? x : 0.2f * x; }

__device__ __forceinline__ float wave_sum64(float v) {
#pragma unroll
    for (int off = 32; off > 0; off >>= 1) v += __shfl_down(v, off);
    return v;   // valid in lane 0
}

// ---------------------------------------------------------------------------
// FC1: 8 nodes/block, 256 thr = 4 waves. wave w: layer = w>>1 (A/B),
// nodes (w&1)*4 .. +3. x rows staged as float4 in LDS; 1 W load feeds 4 FMAs.
// h output padded to 64 floats/row (lanes 60-63 naturally accumulate 0).
// unroll capped at 2: full unroll hoisted 120 W-loads -> 256 VGPR, scratch
// spills (1.3 GB WRITE_SIZE, occupancy 10.8%) measured in round 11.
// ---------------------------------------------------------------------------
__global__ __launch_bounds__(256) void fc1_kernel(
    const float* __restrict__ x,
    const float* __restrict__ WA, const float* __restrict__ alA, const float* __restrict__ arA,
    const float* __restrict__ WB, const float* __restrict__ alB, const float* __restrict__ arB,
    float* __restrict__ hA, float* __restrict__ hB,
    float* __restrict__ elA, float* __restrict__ erA,
    float* __restrict__ elB, float* __restrict__ erB)
{
    __shared__ float4 rows[8][30];         // 8 nodes x 120 floats
    const int base = blockIdx.x * 8;
    const int tid  = threadIdx.x;
    const float4* x4 = (const float4*)(x + (size_t)base * 120);
    if (tid < 240) rows[tid / 30][tid % 30] = x4[tid];
    __syncthreads();

    const int wave  = tid >> 6;
    const int lane  = tid & 63;
    const int layer = wave >> 1;
    const int nd    = (wave & 1) * 4;
    const float* W  = layer ? WB : WA;
    const float* al = layer ? alB : alA;
    const float* ar = layer ? arB : arA;
    float* h  = layer ? hB : hA;
    float* el = layer ? elB : elA;
    float* er = layer ? erB : erA;

    const bool act = lane < 60;
    float a0 = 0.f, a1 = 0.f, a2 = 0.f, a3 = 0.f;
#pragma unroll 2
    for (int kq = 0; kq < 30; ++kq) {
        const float4 r0 = rows[nd + 0][kq];
        const float4 r1 = rows[nd + 1][kq];
        const float4 r2 = rows[nd + 2][kq];
        const float4 r3 = rows[nd + 3][kq];
        const int k = kq * 4;
        const float w0 = act ? W[(k + 0) * 60 + lane] : 0.f;
        const float w1 = act ? W[(k + 1) * 60 + lane] : 0.f;
        const float w2 = act ? W[(k + 2) * 60 + lane] : 0.f;
        const float w3 = act ? W[(k + 3) * 60 + lane] : 0.f;
        a0 += r0.x * w0 + r0.y * w1 + r0.z * w2 + r0.w * w3;
        a1 += r1.x * w0 + r1.y * w1 + r1.z * w2 + r1.w * w3;
        a2 += r2.x * w0 + r2.y * w1 + r2.z * w2 + r2.w * w3;
        a3 += r3.x * w0 + r3.y * w1 + r3.z * w2 + r3.w * w3;
    }

    // store padded rows (lanes 60-63 hold 0)
    h[(size_t)(base + nd + 0) * 64 + lane] = a0;
    h[(size_t)(base + nd + 1) * 64 + lane] = a1;
    h[(size_t)(base + nd + 2) * 64 + lane] = a2;
    h[(size_t)(base + nd + 3) * 64 + lane] = a3;

    const int wj = act ? lane : 59;        // a_i = 0 for lanes >= 60
    const float alv = al[wj], arv = ar[wj];
    float cl, cr;
    cl = wave_sum64(a0 * alv); cr = wave_sum64(a0 * arv);
    if (lane == 0) { el[base + nd + 0] = cl; er[base + nd + 0] = cr; }
    cl = wave_sum64(a1 * alv); cr = wave_sum64(a1 * arv);
    if (lane == 0) { el[base + nd + 1] = cl; er[base + nd + 1] = cr; }
    cl = wave_sum64(a2 * alv); cr = wave_sum64(a2 * arv);
    if (lane == 0) { el[base + nd + 2] = cl; er[base + nd + 2] = cr; }
    cl = wave_sum64(a3 * alv); cr = wave_sum64(a3 * arv);
    if (lane == 0) { el[base + nd + 3] = cl; er[base + nd + 3] = cr; }
}

// ---------------------------------------------------------------------------
// FC post: 4 nodes/block, 4 waves; wave: layer = w>>1, nodes (w&1)*2 .. +1.
// DIN=60 (rows padded 64), DOUT=120 (j0=lane, j1=lane+64 for lane<56).
// unroll capped at 3 (same spill hazard as fc1: 8 W-loads/iter x 15 iters).
// ---------------------------------------------------------------------------
__global__ __launch_bounds__(256) void fc_post(
    const float* __restrict__ aggA, const float* __restrict__ aggB,  // [N,64]
    const float* __restrict__ WA, const float* __restrict__ bA,
    const float* __restrict__ WB, const float* __restrict__ bB,
    float* __restrict__ outA, float* __restrict__ outB)              // [N,120]
{
    __shared__ float4 rows[2][4][16];
    const int base = blockIdx.x * 4;
    const int tid  = threadIdx.x;
    if (tid < 128) {
        const int l = tid >> 6, r = (tid >> 4) & 3, q = tid & 15;
        const float4* srcp = (const float4*)((l ? aggB : aggA) + (size_t)(base + r) * 64);
        rows[l][r][q] = srcp[q];
    }
    __syncthreads();

    const int wave  = tid >> 6;
    const int lane  = tid & 63;
    const int layer = wave >> 1;
    const int nd    = (wave & 1) * 2;
    const float* W = layer ? WB : WA;
    const float* b = layer ? bB : bA;
    float* out = layer ? outB : outA;

    const int j0 = lane, j1 = lane + 64;
    const bool hi = lane < 56;             // j1 < 120
    float a00 = 0.f, a01 = 0.f, a10 = 0.f, a11 = 0.f;
#pragma unroll 3
    for (int kq = 0; kq < 15; ++kq) {      // k < 60 (skip pad quad)
        const float4 r0 = rows[layer][nd + 0][kq];
        const float4 r1 = rows[layer][nd + 1][kq];
        const int k = kq * 4;
        const float wa0 = W[(k + 0) * 120 + j0];
        const float wa1 = W[(k + 1) * 120 + j0];
        const float wa2 = W[(k + 2) * 120 + j0];
        const float wa3 = W[(k + 3) * 120 + j0];
        a00 += r0.x * wa0 + r0.y * wa1 + r0.z * wa2 + r0.w * wa3;
        a10 += r1.x * wa0 + r1.y * wa1 + r1.z * wa2 + r1.w * wa3;
        if (hi) {
            const float wb0 = W[(k + 0) * 120 + j1];
            const float wb1 = W[(k + 1) * 120 + j1];
            const float wb2 = W[(k + 2) * 120 + j1];
            const float wb3 = W[(k + 3) * 120 + j1];
            a01 += r0.x * wb0 + r0.y * wb1 + r0.z * wb2 + r0.w * wb3;
            a11 += r1.x * wb0 + r1.y * wb1 + r1.z * wb2 + r1.w * wb3;
        }
    }
    const size_t n0 = base + nd + 0, n1 = base + nd + 1;
    out[n0 * 120 + j0] = a00 + b[j0];
    out[n1 * 120 + j0] = a10 + b[j0];
    if (hi) {
        out[n0 * 120 + j1] = a01 + b[j1];
        out[n1 * 120 + j1] = a11 + b[j1];
    }
}

// ---------------------------------------------------------------------------
// prep: vl = W @ al, vr = W @ ar for pair-2 layers, padded to 64 with zeros.
// ---------------------------------------------------------------------------
__global__ __launch_bounds__(64) void prep_vec(
    const float* __restrict__ W2, const float* __restrict__ al2, const float* __restrict__ ar2,
    const float* __restrict__ W4, const float* __restrict__ al4, const float* __restrict__ ar4,
    float* __restrict__ vlA, float* __restrict__ vrA,
    float* __restrict__ vlB, float* __restrict__ vrB)
{
    const int t = threadIdx.x;
    float a = 0.f, b = 0.f, c = 0.f, d = 0.f;
    if (t < 60) {
        for (int j = 0; j < 120; ++j) {
            const float w2 = W2[t * 120 + j];
            const float w4 = W4[t * 120 + j];
            a += w2 * al2[j];  b += w2 * ar2[j];
            c += w4 * al4[j];  d += w4 * ar4[j];
        }
    }
    vlA[t] = a; vrA[t] = b; vlB[t] = c; vrB[t] = d;
}

// ---------------------------------------------------------------------------
// Coarse counting sort: hist -> scan -> partition (packed) -> bucket sort.
// ---------------------------------------------------------------------------
__global__ __launch_bounds__(512) void zero_coarse(int* __restrict__ ccnt)
{
    const int i = threadIdx.x;
    if (i < NB_C) ccnt[i] = 0;
}

__global__ __launch_bounds__(256) void coarse_hist(
    const int* __restrict__ dst, int* __restrict__ ccnt)
{
    __shared__ int lh[NB_C];
    for (int i = threadIdx.x; i < NB_C; i += 256) lh[i] = 0;
    __syncthreads();
    for (int e = blockIdx.x * 256 + threadIdx.x; e < NEDGE; e += gridDim.x * 256)
        atomicAdd(&lh[dst[e] >> 8], 1);
    __syncthreads();
    for (int i = threadIdx.x; i < NB_C; i += 256)
        if (lh[i]) atomicAdd(&ccnt[i], lh[i]);
}

__global__ __launch_bounds__(512) void coarse_scan(
    const int* __restrict__ ccnt, int* __restrict__ coff, int* __restrict__ gcur,
    int* __restrict__ offsets)
{
    __shared__ int sm[512];
    const int t = threadIdx.x;
    const int v = (t < NB_C) ? ccnt[t] : 0;
    sm[t] = v; __syncthreads();
    for (int d = 1; d < 512; d <<= 1) {
        int u = (t >= d) ? sm[t - d] : 0;
        __syncthreads();
        sm[t] += u;
        __syncthreads();
    }
    if (t < NB_C) { const int ex = sm[t] - v; coff[t] = ex; gcur[t] = ex; }
    if (t == NB_C - 1) coff[NB_C] = sm[t];
    if (t == 0) offsets[NNODE] = NEDGE;
}

__global__ __launch_bounds__(256) void partition_kernel(
    const int* __restrict__ src, const int* __restrict__ dst,
    int* __restrict__ gcur, unsigned* __restrict__ packed)
{
    __shared__ int lh[NB_C];
    __shared__ int lcur[NB_C];
    const int t    = threadIdx.x;
    const int base = blockIdx.x * TILE_E;

    for (int i = t; i < NB_C; i += 256) lh[i] = 0;
    __syncthreads();
#pragma unroll
    for (int k = 0; k < TILE_E / 256; ++k) {
        const int e = base + k * 256 + t;
        if (e < NEDGE) atomicAdd(&lh[dst[e] >> 8], 1);
    }
    __syncthreads();
    for (int i = t; i < NB_C; i += 256) {
        const int c = lh[i];
        lcur[i] = c ? atomicAdd(&gcur[i], c) : 0;
    }
    __syncthreads();
#pragma unroll
    for (int k = 0; k < TILE_E / 256; ++k) {
        const int e = base + k * 256 + t;
        if (e < NEDGE) {
            const int d = dst[e];
            const int pos = atomicAdd(&lcur[d >> 8], 1);
            packed[pos] = ((unsigned)(d & 255) << 17) | (unsigned)src[e];
        }
    }
}

__global__ __launch_bounds__(256) void bucket_sort(
    const unsigned* __restrict__ packed, const int* __restrict__ coff,
    int* __restrict__ offsets, int* __restrict__ sorted)
{
    __shared__ int cnt[256];
    __shared__ int sm[256];
    __shared__ int cur[256];
    const int b   = blockIdx.x;
    const int t   = threadIdx.x;
    const int beg = coff[b];
    const int end = coff[b + 1];
    const int node_base = b * BK;

    cnt[t] = 0; __syncthreads();
    for (int i = beg + t; i < end; i += 256)
        atomicAdd(&cnt[packed[i] >> 17], 1);
    __syncthreads();
    const int v = cnt[t];
    sm[t] = v; __syncthreads();
    for (int d = 1; d < 256; d <<= 1) {
        int u = (t >= d) ? sm[t - d] : 0;
        __syncthreads();
        sm[t] += u;
        __syncthreads();
    }
    const int off_n = beg + sm[t] - v;
    if (node_base + t < NNODE) offsets[node_base + t] = off_n;
    cur[t] = off_n;
    __syncthreads();
    for (int i = beg + t; i < end; i += 256) {
        const unsigned p = packed[i];
        const int pos = atomicAdd(&cur[p >> 17], 1);
        sorted[pos] = (int)(p & 0x1FFFFu);
    }
}

// ---------------------------------------------------------------------------
// Aggregate over padded [N,64] rows, 4 edges per wave-iteration.
// Lanes: group g = lane>>4 handles edge i+g; j = lane&15 indexes the row's
// 16 float4s. Group partials folded with shfl_xor(16/32). wave0=A, wave1=B.
// FUSED: adds bias and computes pair-2 el/er = dot(out, vl/vr).
// segment_max skipped (softmax shift-invariant; scores O(1), no overflow).
// ---------------------------------------------------------------------------
template <bool FUSED>
__global__ __launch_bounds__(128) void aggregate64(
    const int* __restrict__ sorted_src, const int* __restrict__ offsets,
    const float* __restrict__ elA, const float* __restrict__ erA,
    const float* __restrict__ elB, const float* __restrict__ erB,
    const float* __restrict__ hA, const float* __restrict__ hB,   // [N,64]
    const float* __restrict__ bA, const float* __restrict__ bB,
    const float* __restrict__ vlA, const float* __restrict__ vrA, // [64] padded
    const float* __restrict__ vlB, const float* __restrict__ vrB,
    float* __restrict__ outA, float* __restrict__ outB,           // [N,64]
    float* __restrict__ el2A, float* __restrict__ er2A,
    float* __restrict__ el2B, float* __restrict__ er2B)
{
    const int n    = blockIdx.x;
    const int wave = threadIdx.x >> 6;
    const int lane = threadIdx.x & 63;
    const int g    = lane >> 4;
    const int j    = lane & 15;

    const float* el  = wave ? elB : elA;
    const float  ern = (wave ? erB : erA)[n];
    const float4* h4 = (const float4*)(wave ? hB : hA);
    float4* o4 = (float4*)(wave ? outB : outA);

    const int start = offsets[n];
    const int end   = offsets[n + 1];

    float4 acc = {0.f, 0.f, 0.f, 0.f};
    float den = 0.f;

    for (int i = start; i < end; i += 8) {
        const int i0 = i + g, i1 = i + 4 + g;
        const int c0 = min(i0, end - 1), c1 = min(i1, end - 1);
        const int s0 = sorted_src[c0];
        const int s1 = sorted_src[c1];
        const float w0 = (i0 < end) ? expf(leaky(el[s0] + ern)) : 0.f;
        const float w1 = (i1 < end) ? expf(leaky(el[s1] + ern)) : 0.f;
        const float4 v0 = h4[(size_t)s0 * 16 + j];
        const float4 v1 = h4[(size_t)s1 * 16 + j];
        den += w0 + w1;
        acc.x += w0 * v0.x + w1 * v1.x;
        acc.y += w0 * v0.y + w1 * v1.y;
        acc.z += w0 * v0.z + w1 * v1.z;
        acc.w += w0 * v0.w + w1 * v1.w;
    }

    // fold the 4 edge-groups
    den   += __shfl_xor(den, 16);   den   += __shfl_xor(den, 32);
    acc.x += __shfl_xor(acc.x, 16); acc.x += __shfl_xor(acc.x, 32);
    acc.y += __shfl_xor(acc.y, 16); acc.y += __shfl_xor(acc.y, 32);
    acc.z += __shfl_xor(acc.z, 16); acc.z += __shfl_xor(acc.z, 32);
    acc.w += __shfl_xor(acc.w, 16); acc.w += __shfl_xor(acc.w, 32);

    const float inv = 1.f / (den + 1e-9f);
    float4 o;
    o.x = acc.x * inv; o.y = acc.y * inv; o.z = acc.z * inv; o.w = acc.w * inv;
    if (FUSED) {
        if (j < 15) {       // bias has exactly 15 float4s; pad quad = 0
            const float4 bb = ((const float4*)(wave ? bB : bA))[j];
            o.x += bb.x; o.y += bb.y; o.z += bb.z; o.w += bb.w;
        }
    }
    if (g == 0) o4[(size_t)n * 16 + j] = o;

    if (FUSED) {
        const float4* vl4 = (const float4*)(wave ? vlB : vlA);
        const float4* vr4 = (const float4*)(wave ? vrB : vrA);
        const float4 l = vl4[j], r = vr4[j];
        float pl = o.x * l.x + o.y * l.y + o.z * l.z + o.w * l.w;
        float pr = o.x * r.x + o.y * r.y + o.z * r.z + o.w * r.w;
#pragma unroll
        for (int off = 1; off < 16; off <<= 1) {
            pl += __shfl_xor(pl, off);
            pr += __shfl_xor(pr, off);
        }
        if (lane == 0) {
            if (wave) { el2B[n] = pl; er2B[n] = pr; }
            else      { el2A[n] = pl; er2A[n] = pr; }
        }
    }
}

// ---------------------------------------------------------------------------
extern "C" void kernel_launch(void* const* d_in, const int* in_sizes, int n_in,
                              void* d_out, int out_size, void* d_ws, size_t ws_size,
                              hipStream_t stream)
{
    const float* x   = (const float*)d_in[0];
    const int* ei0   = (const int*)d_in[1];
    const int* ei1   = (const int*)d_in[2];
    const float* W1  = (const float*)d_in[3];
    const float* al1 = (const float*)d_in[4];
    const float* ar1 = (const float*)d_in[5];
    const float* b1  = (const float*)d_in[6];
    const float* W2  = (const float*)d_in[7];
    const float* al2 = (const float*)d_in[8];
    const float* ar2 = (const float*)d_in[9];
    const float* b2  = (const float*)d_in[10];
    const float* W3  = (const float*)d_in[11];
    const float* al3 = (const float*)d_in[12];
    const float* ar3 = (const float*)d_in[13];
    const float* b3  = (const float*)d_in[14];
    const float* W4  = (const float*)d_in[15];
    const float* al4 = (const float*)d_in[16];
    const float* ar4 = (const float*)d_in[17];
    const float* b4  = (const float*)d_in[18];

    const int* src0 = ei0;  const int* dst0 = ei0 + NEDGE;
    const int* src1 = ei1;  const int* dst1 = ei1 + NEDGE;

    float* out_a = (float*)d_out;                 // final h_a [N,120]
    float* out_f = out_a + (size_t)NNODE * 120;   // final h_f [N,120]
    // pair-1 aggregated outputs (padded [N,64]) live in d_out temporarily;
    // consumed by pair-2 aggregate before fc_post overwrites the region.
    float* h1 = out_a;                            // [N,64]
    float* h2 = out_a + (size_t)NNODE * 64;       // [N,64]

    // ---- workspace layout (floats, all offsets 16B-aligned) ----
    float* hA    = (float*)d_ws;                  // [N,64] fc1-A; later pair-2 agg A
    float* hB    = hA + (size_t)NNODE * 64;       // [N,64] fc1-B; later pair-2 agg B
    float* el1A  = hB + (size_t)NNODE * 64;
    float* er1A  = el1A + NNODE;
    float* el1B  = er1A + NNODE;
    float* er1B  = el1B + NNODE;
    float* el2A  = er1B + NNODE;
    float* er2A  = el2A + NNODE;
    float* el2B  = er2A + NNODE;
    float* er2B  = el2B + NNODE;
    float* vlA   = er2B + NNODE;                  // [64] padded
    float* vrA   = vlA + 64;
    float* vlB   = vrA + 64;
    float* vrB   = vlB + 64;
    int*   ccnt    = (int*)(vrB + 64);            // [NB_C]
    int*   coff    = ccnt + NB_C;                 // [NB_C+1]
    int*   gcur    = coff + NB_C + 1;             // [NB_C]
    int*   offsets = gcur + NB_C;                 // [N+1]
    unsigned* packed = (unsigned*)(offsets + NNODE + 1);  // [E]
    int*   sorted  = (int*)(packed + NEDGE);      // [E]

    // ---------------- pair 1: layers 1 (A) / 3 (B) on edge_index0 ----------
    prep_vec<<<1, 64, 0, stream>>>(W2, al2, ar2, W4, al4, ar4, vlA, vrA, vlB, vrB);
    fc1_kernel<<<NNODE / 8, 256, 0, stream>>>(
        x, W1, al1, ar1, W3, al3, ar3, hA, hB, el1A, er1A, el1B, er1B);
    zero_coarse<<<1, 512, 0, stream>>>(ccnt);
    coarse_hist<<<256, 256, 0, stream>>>(dst0, ccnt);
    coarse_scan<<<1, 512, 0, stream>>>(ccnt, coff, gcur, offsets);
    partition_kernel<<<NTILES, 256, 0, stream>>>(src0, dst0, gcur, packed);
    bucket_sort<<<NB_C, 256, 0, stream>>>(packed, coff, offsets, sorted);
    aggregate64<true><<<NNODE, 128, 0, stream>>>(
        sorted, offsets, el1A, er1A, el1B, er1B, hA, hB, b1, b3,
        vlA, vrA, vlB, vrB, h1, h2, el2A, er2A, el2B, er2B);

    // ---------------- pair 2: layers 2 (A) / 4 (B) on edge_index1 ----------
    zero_coarse<<<1, 512, 0, stream>>>(ccnt);
    coarse_hist<<<256, 256, 0, stream>>>(dst1, ccnt);
    coarse_scan<<<1, 512, 0, stream>>>(ccnt, coff, gcur, offsets);
    partition_kernel<<<NTILES, 256, 0, stream>>>(src1, dst1, gcur, packed);
    bucket_sort<<<NB_C, 256, 0, stream>>>(packed, coff, offsets, sorted);
    // aggregate 60-wide (padded 64) inputs h1/h2 with pair-2 attention
    // weights; W applied after aggregation (linearity).
    aggregate64<false><<<NNODE, 128, 0, stream>>>(
        sorted, offsets, el2A, er2A, el2B, er2B, h1, h2, nullptr, nullptr,
        nullptr, nullptr, nullptr, nullptr, hA, hB,
        nullptr, nullptr, nullptr, nullptr);
    fc_post<<<NNODE / 4, 256, 0, stream>>>(hA, hB, W2, b2, W4, b4, out_a, out_f);
}